// Round 3
// baseline (233.376 us; speedup 1.0000x reference)
//
#include <hip/hip_runtime.h>
#include <hip/hip_bf16.h>

// B=4, C=256, H=W=64, O=256, K=3, PAD=2, DIL=2; offset conv: 18ch 3x3 p1 d1.
// R11: VALU + redundancy attack. R10 post-mortem: fusion neutral (deform
// +28us == removed kernel) because staging cost moved, not removed. Fixes:
// (1) staging descriptors (soff[12]) computed ONCE per thread, reused by all
//     stagings; bf16 pack via __float22bfloat162_rn (HW cvt_pk);
// (2) pass-1 cb order 3->0 leaves dbuf = {cb0,cb1} so pass 2 stages only
//     cb2,cb3: 8 stagings -> 6; pass 1 software-pipelined (issue loads
//     before conv, commit after);
// (3) prep rewritten coalesced (72 contiguous floats/thread, 18x float4)
//     and absorbs the deform_w->out copy (memcpy dispatch removed).
// Verified math (MFMA layouts, sampling, phase-B) byte-identical to R10.

typedef __attribute__((ext_vector_type(8))) short short8;
typedef __attribute__((ext_vector_type(4))) float floatx4;

__device__ inline unsigned short f2bf(float f) {  // RNE fp32 -> bf16 bits
  unsigned int u = __float_as_uint(f);
  u += 0x7fff + ((u >> 16) & 1);
  return (unsigned short)(u >> 16);
}
__device__ inline float bflo(unsigned int u) { return __uint_as_float(u << 16); }
__device__ inline float bfhi(unsigned int u) {
  return __uint_as_float(u & 0xffff0000u);
}
// packed fp32x2 -> bf16x2 (RNE); standard cast so compiler emits cvt_pk
__device__ __forceinline__ unsigned int pkbf(float a, float b) {
  __hip_bfloat162 h = __float22bfloat162_rn(make_float2(a, b));
  unsigned int u;
  __builtin_memcpy(&u, &h, 4);
  return u;
}
__device__ __forceinline__ short8 pack4(unsigned int u0, unsigned int u1,
                                        unsigned int u2, unsigned int u3) {
  short8 b;
  b[0] = (short)(u0 & 0xffff);
  b[1] = (short)(u0 >> 16);
  b[2] = (short)(u1 & 0xffff);
  b[3] = (short)(u1 >> 16);
  b[4] = (short)(u2 & 0xffff);
  b[5] = (short)(u2 >> 16);
  b[6] = (short)(u3 & 0xffff);
  b[7] = (short)(u3 >> 16);
  return b;
}

// ---------------------------------------------------------------------------
// prep (coalesced). Thread g<8192: (o = g>>5, c8 = g&31) reads 72 contiguous
// floats dw[o][c8*8 .. c8*8+7][0..8] as 18x float4, emits 9 short8 frags:
// wfrag[ci=cb*9+n][mt=o>>4][kt=(c8>>2)&1][lane=(c8&3)*16+(o&15)][j],
// cb = c8>>3 (c = c8*8+j = cb*64+kt*32+lh*8+j). g in [8192,9216): same for
// wfragA (o<18 real, else zeros). All threads then grid-stride copy dw ->
// out tail (replaces hipMemcpyAsync dispatch).
// ---------------------------------------------------------------------------
__global__ __launch_bounds__(256) void prep_kernel(
    const float* __restrict__ dw, const float* __restrict__ ow,
    unsigned short* __restrict__ wfrag, unsigned short* __restrict__ wfragA,
    float* __restrict__ dwcopy) {
  int g = blockIdx.x * 256 + threadIdx.x;
  if (g < 8192) {
    int o = g >> 5, c8 = g & 31;
    int cb = c8 >> 3, kt = (c8 >> 2) & 1, lh = c8 & 3;
    int mt = o >> 4, lane = lh * 16 + (o & 15);
    float f[72];
    const float4* src = (const float4*)(dw + o * 2304 + c8 * 72);
#pragma unroll
    for (int q = 0; q < 18; ++q) {
      float4 t4 = src[q];
      f[4 * q] = t4.x;
      f[4 * q + 1] = t4.y;
      f[4 * q + 2] = t4.z;
      f[4 * q + 3] = t4.w;
    }
#pragma unroll
    for (int n = 0; n < 9; ++n) {
      int ci = cb * 9 + n;
      short8 v;
#pragma unroll
      for (int j = 0; j < 8; ++j) v[j] = (short)f2bf(f[j * 9 + n]);
      *((short8*)wfrag + ((ci * 16 + mt) * 2 + kt) * 64 + lane) = v;
    }
  } else if (g < 9216) {
    int t = g - 8192;
    int o = t >> 5, c8 = t & 31;
    int cb = c8 >> 3, kt = (c8 >> 2) & 1, lh = c8 & 3;
    int mt = o >> 4, lane = lh * 16 + (o & 15);
    float f[72];
    if (o < 18) {
      const float4* src = (const float4*)(ow + o * 2304 + c8 * 72);
#pragma unroll
      for (int q = 0; q < 18; ++q) {
        float4 t4 = src[q];
        f[4 * q] = t4.x;
        f[4 * q + 1] = t4.y;
        f[4 * q + 2] = t4.z;
        f[4 * q + 3] = t4.w;
      }
    } else {
#pragma unroll
      for (int q = 0; q < 72; ++q) f[q] = 0.f;
    }
#pragma unroll
    for (int n = 0; n < 9; ++n) {
      int ci = cb * 9 + n;
      short8 v;
#pragma unroll
      for (int j = 0; j < 8; ++j) v[j] = (short)f2bf(f[j * 9 + n]);
      *((short8*)wfragA + ((ci * 2 + kt) * 2 + mt) * 64 + lane) = v;
    }
  }
  // coalesced deform_w copy to out tail
  const float4* s = (const float4*)dw;
  float4* d = (float4*)dwcopy;
  for (int i = g; i < 147456; i += 10240) d[i] = s[i];
}

// ---------------------------------------------------------------------------
// Staging split into issue (global->regs, soff precomputed) / commit
// (regs->LDS, cvt_pk). soff[k] = pl*8192 + gy*64 + gx (valid) else -1;
// element e = tid + k*512 of [pair=32][ry=15][rx=12 (11 valid)].
// ---------------------------------------------------------------------------
__device__ __forceinline__ void issue_loads(const float* __restrict__ src,
                                            const int* soff, float* pr0,
                                            float* pr1) {
#pragma unroll
  for (int k = 0; k < 12; ++k) {
    pr0[k] = 0.f;
    pr1[k] = 0.f;
    int so = soff[k];
    if (so >= 0) {
      pr0[k] = src[so];
      pr1[k] = src[so + 4096];
    }
  }
}
__device__ __forceinline__ void commit_stage(unsigned int* __restrict__ dst,
                                             const float* pr0, const float* pr1,
                                             int tid) {
#pragma unroll
  for (int k = 0; k < 11; ++k) dst[tid + k * 512] = pkbf(pr0[k], pr1[k]);
  if (tid < 128) dst[tid + 5632] = pkbf(pr0[11], pr1[11]);
}

// ---------------------------------------------------------------------------
// Deform sampler for one chunk (cb, n), 8x4 px tile: thread = (grp = tid>>5,
// px = tid&31). grp covers channel-pairs {2*grp, 2*grp+1} of the cb (4
// channels); 8 corner u32 reads -> 2 cvt_pk -> one ds_write_b64 into colf.
// colf layout [nt=2][kt=2][lane=64][j=8]: lane = (px&15)|(kq<<4),
// cl (=kl) = grp*4 + 2q + h -> kt=grp>>3, kq=(grp>>1)&3, j=(grp&1)*4+2q+h.
// ---------------------------------------------------------------------------
__device__ __forceinline__ void sample_chunk(
    const unsigned int* __restrict__ xpcb, int n,
    unsigned short* __restrict__ colf, int grp, int px,
    const float (*sw4)[32][4], const int (*scoff)[32]) {
  float4 wq = *(const float4*)&sw4[n][px][0];
  const unsigned int* bp = xpcb + grp * 360 + scoff[n][px];
  unsigned int ua0 = bp[0], ub0 = bp[1], uc0 = bp[12], ud0 = bp[13];
  unsigned int ua1 = bp[180], ub1 = bp[181], uc1 = bp[192], ud1 = bp[193];
  float lo0 = wq.x * bflo(ua0) + wq.y * bflo(ub0) + wq.z * bflo(uc0) +
              wq.w * bflo(ud0);
  float hi0 = wq.x * bfhi(ua0) + wq.y * bfhi(ub0) + wq.z * bfhi(uc0) +
              wq.w * bfhi(ud0);
  float lo1 = wq.x * bflo(ua1) + wq.y * bflo(ub1) + wq.z * bflo(uc1) +
              wq.w * bflo(ud1);
  float hi1 = wq.x * bfhi(ua1) + wq.y * bfhi(ub1) + wq.z * bfhi(uc1) +
              wq.w * bfhi(ud1);
  uint2 vv = make_uint2(pkbf(lo0, hi0), pkbf(lo1, hi1));
  int kt = grp >> 3, kq = (grp >> 1) & 3, nt = px >> 4, jo = (grp & 1) * 4;
  *(uint2*)&colf[((nt * 2 + kt) * 64 + ((px & 15) | (kq << 4))) * 8 + jo] = vv;
}

// ---------------------------------------------------------------------------
// Fused: offset conv (pass 1) + bilinear sample + bf16 MFMA GEMM (pass 2).
// 8x4 px tile, 256 o, 512 thr (8 waves), 512 blocks -> 2 blocks/CU.
// Pass 1: cb 3->0 pipelined {issue cb-1 loads; conv(cb) 9 MFMA; commit
//   cb-1; barrier}; ends with buf0=cb0, buf1=cb1. kt-halves reduced via LDS
//   (aliased into colf); s_off -> phase-B offsets/weights in LDS.
// Pass 2: chunks (cb 0..3)x(n 0..8); cb0/cb1 tiles inherited from pass 1;
//   cb2/cb3 staged via issue(n==6)/commit(n==7); colf dbuf; ONE barrier per
//   chunk: MFMA(ci) || sample(ci+1).
// ---------------------------------------------------------------------------
__global__ __launch_bounds__(512, 4) void deform_kernel(
    const float* __restrict__ x, const float* __restrict__ obias,
    const unsigned short* __restrict__ wfragA,
    const unsigned short* __restrict__ wfrag, const float* __restrict__ bias,
    float* __restrict__ out) {
  int tid = threadIdx.x;
  int b = blockIdx.y, tile = blockIdx.x;
  int h0 = (tile >> 4) * 8, w0 = (tile & 15) * 4;
  int lane = tid & 63, wv = tid >> 6;
  int px = tid & 31, grp = tid >> 5;

  __shared__ unsigned int s_xp[2][5760];  // [buf][pair*180 + ry*12 + rx]
  __shared__ __align__(16) unsigned short s_colf[2][2048];
  __shared__ __align__(16) float s_w4[9][32][4];
  __shared__ int s_coff[9][32];

  const float* xb = x + (size_t)b * 256 * 4096;

  // staging descriptors, computed ONCE (reused by all 6 stagings)
  int soff[12];
#pragma unroll
  for (int k = 0; k < 12; ++k) {
    int e = tid + k * 512;
    int v = -1;
    if (e < 5760) {
      int pl = e / 180, pos = e - pl * 180;
      int ry = pos / 12, rx = pos - ry * 12;
      int gy = h0 - 3 + ry, gx = w0 - 3 + rx;
      if (rx < 11 && gy >= 0 && gy < 64 && gx >= 0 && gx < 64)
        v = pl * 8192 + gy * 64 + gx;
    }
    soff[k] = v;
  }

  float pr0[12], pr1[12];

  // ---------------- pass 1: offset conv (18x32 tile) ----------------
  // wave wv -> (mtA = wv>>2, tnA = (wv>>1)&1, ktA = wv&1); 1 MFMA per (cb,t).
  int mtA = wv >> 2, tnA = (wv >> 1) & 1, ktA = wv & 1;
  int pA = tnA * 16 + (lane & 15);  // local px 0..31
  int pyA = pA >> 2, pxA = pA & 3;
  int kqA = lane >> 4;
  const short8* wAg = (const short8*)wfragA;
  floatx4 aoff = (floatx4)(0.f);

  // prologue: stage cb3 -> buf1
  issue_loads(xb + 3 * 262144, soff, pr0, pr1);
  commit_stage(s_xp[1], pr0, pr1, tid);
  __syncthreads();

  for (int i = 0; i < 4; ++i) {
    int cb = 3 - i;
    if (cb > 0) issue_loads(xb + (cb - 1) * 262144, soff, pr0, pr1);
    const unsigned int* xp = s_xp[cb & 1];
    const unsigned int* bp0 =
        xp + (ktA * 16 + kqA * 4) * 180 + (pyA + 2) * 12 + (pxA + 2);
    for (int t = 0; t < 9; ++t) {
      int ty = t / 3, tx = t - ty * 3;
      int ci = cb * 9 + t;
      short8 aA = wAg[((ci * 2 + ktA) * 2 + mtA) * 64 + lane];
      const unsigned int* bp = bp0 + ty * 12 + tx;
      short8 bfr = pack4(bp[0], bp[180], bp[360], bp[540]);
      aoff = __builtin_amdgcn_mfma_f32_16x16x32_bf16(aA, bfr, aoff, 0, 0, 0);
    }
    if (cb > 0) commit_stage(s_xp[(cb - 1) & 1], pr0, pr1, tid);
    __syncthreads();
  }
  // post: buf0 = cb0, buf1 = cb1 (pass 2 inherits both)

  // kt-half reduction through LDS (aliased into colf; colf unused yet)
  float* s_red = (float*)&s_colf[0][0];  // 4 combos x 64 lanes x 4 = 4KB
  float* s_off = s_red + 1024;           // [o=18][px=32] raw conv sums
  if (ktA == 1) {
#pragma unroll
    for (int r = 0; r < 4; ++r)
      s_red[((mtA * 2 + tnA) * 64 + lane) * 4 + r] = aoff[r];
  }
  __syncthreads();
  if (ktA == 0) {
#pragma unroll
    for (int r = 0; r < 4; ++r) {
      float v = aoff[r] + s_red[((mtA * 2 + tnA) * 64 + lane) * 4 + r];
      int o = mtA * 16 + kqA * 4 + r;  // C/D row = quad*4+r (R6-verified)
      if (o < 18) s_off[o * 32 + pA] = v;
    }
  }
  __syncthreads();

  // phase B (R6-verified math): bias + clip fused; s_off holds raw sums.
  if (tid < 288) {
    int n = tid >> 5, pe = tid & 31;
    int hy = h0 + (pe >> 2), wx = w0 + (pe & 3);
    float dy = s_off[(2 * n) * 32 + pe] + obias[2 * n];
    float dx = s_off[(2 * n + 1) * 32 + pe] + obias[2 * n + 1];
    dy = fminf(fmaxf(dy, -1.f), 1.f);
    dx = fminf(fmaxf(dx, -1.f), 1.f);
    float fy = dy + (float)(hy - 2 + (n / 3) * 2);
    float fx = dx + (float)(wx - 2 + (n % 3) * 2);
    float y0f = floorf(fy), x0f = floorf(fx);
    float wy1 = fy - y0f, wx1 = fx - x0f;
    float wy0 = 1.f - wy1, wx0 = 1.f - wx1;
    s_coff[n][pe] = ((int)y0f - (h0 - 3)) * 12 + ((int)x0f - (w0 - 3));
    s_w4[n][pe][0] = wy0 * wx0;
    s_w4[n][pe][1] = wy0 * wx1;
    s_w4[n][pe][2] = wy1 * wx0;
    s_w4[n][pe][3] = wy1 * wx1;
  }
  __syncthreads();

  // ---------------- pass 2: sample + GEMM ----------------
  // prologue: sample chunk 0 (cb0 from buf0, n0) -> colf[0]
  sample_chunk(s_xp[0], 0, s_colf[0], grp, px, s_w4, s_coff);
  __syncthreads();

  floatx4 acc[2][2];
#pragma unroll
  for (int i = 0; i < 2; ++i)
#pragma unroll
    for (int j = 0; j < 2; ++j) acc[i][j] = (floatx4)(0.f);

  for (int cb = 0; cb < 4; ++cb) {
    for (int n = 0; n < 9; ++n) {
      int ci = cb * 9 + n;
      // A-frags for chunk ci (global/L2; consumed at MFMA below)
      short8 areg[2][2];
      const short8* wg = (const short8*)wfrag + (size_t)ci * 2048;
#pragma unroll
      for (int kt = 0; kt < 2; ++kt)
#pragma unroll
        for (int mi = 0; mi < 2; ++mi)
          areg[kt][mi] = wg[((wv * 2 + mi) * 2 + kt) * 64 + lane];

      // staging for cb+1 in {2,3} only (cb0/cb1 inherited from pass 1);
      // commit n==7 barrier-separated from first read (phase n==8 sampling)
      if (n == 6 && (cb == 1 || cb == 2))
        issue_loads(xb + (cb + 1) * 262144, soff, pr0, pr1);
      if (n == 7 && (cb == 1 || cb == 2))
        commit_stage(s_xp[(cb + 1) & 1], pr0, pr1, tid);

      // sample chunk ci+1 -> colf[(ci+1)&1]
      if (ci + 1 < 36) {
        int nn = n + 1, cbn = cb;
        if (nn == 9) {
          nn = 0;
          cbn = cb + 1;
        }
        sample_chunk(s_xp[cbn & 1], nn, s_colf[(ci + 1) & 1], grp, px, s_w4,
                     s_coff);
      }

      // MFMA chunk ci from colf[ci&1]
      const unsigned short* cf = s_colf[ci & 1];
#pragma unroll
      for (int kt = 0; kt < 2; ++kt) {
        short8 bfr[2];
#pragma unroll
        for (int tn = 0; tn < 2; ++tn)
          bfr[tn] = *(const short8*)&cf[((tn * 2 + kt) * 64 + lane) * 8];
#pragma unroll
        for (int mi = 0; mi < 2; ++mi)
#pragma unroll
          for (int tn = 0; tn < 2; ++tn)
            acc[mi][tn] = __builtin_amdgcn_mfma_f32_16x16x32_bf16(
                areg[kt][mi], bfr[tn], acc[mi][tn], 0, 0, 0);
      }
      __syncthreads();
    }
  }

  // epilogue (R5-verified C/D layout): col=lane&15, row=quad*4+r
  int quad = lane >> 4, col = lane & 15;
#pragma unroll
  for (int mi = 0; mi < 2; ++mi)
#pragma unroll
    for (int tn = 0; tn < 2; ++tn) {
      int pxo = tn * 16 + col;
      int h = h0 + (pxo >> 2), w = w0 + (pxo & 3);
#pragma unroll
      for (int r = 0; r < 4; ++r) {
        int o = wv * 32 + mi * 16 + quad * 4 + r;
        out[(((size_t)b * 256 + o) * 64 + h) * 64 + w] =
            acc[mi][tn][r] + bias[o];
      }
    }
}

extern "C" void kernel_launch(void* const* d_in, const int* in_sizes, int n_in,
                              void* d_out, int out_size, void* d_ws,
                              size_t ws_size, hipStream_t stream) {
  (void)in_sizes; (void)n_in; (void)out_size; (void)ws_size;
  const float* x        = (const float*)d_in[0];  // (4,256,64,64)
  const float* offset_w = (const float*)d_in[1];  // (18,256,3,3)
  const float* offset_b = (const float*)d_in[2];  // (18,)
  const float* deform_w = (const float*)d_in[3];  // (256,256,3,3)
  const float* deform_b = (const float*)d_in[4];  // (256,)
  float* out = (float*)d_out;

  unsigned short* wfrag = (unsigned short*)d_ws;  // 589824 bf16
  unsigned short* wfragA = wfrag + 589824;        // 73728 bf16

  prep_kernel<<<40, 256, 0, stream>>>(deform_w, offset_w, wfrag, wfragA,
                                      out + 4194304);
  deform_kernel<<<dim3(128, 4), 512, 0, stream>>>(x, offset_b, wfragA, wfrag,
                                                  deform_b, out);
}

// Round 4
// 156.239 us; speedup vs baseline: 1.4937x; 1.4937x over previous
//
#include <hip/hip_runtime.h>
#include <hip/hip_bf16.h>

// B=4, C=256, H=W=64, O=256, K=3, PAD=2, DIL=2; offset conv: 18ch 3x3 p1 d1.
// R12: stage-ONCE. R11 post-mortem: persistent reg arrays (soff/pr) caused
// scratch spill (WRITE 32->292MB, deform 175us) -> reverted. Root cost per
// R10 counters: x staged 8x per block (FETCH 143MB vs 16.7MB unique).
// New structure: 8x8 tile (R8-verified layouts), 256 blocks = 1/CU, ALL 4
// cb x-tiles resident in LDS (4x30KB + colf 16KB + tables ~= 147KB < 160KB):
//   - single staging pass (desc computed once/elem, 8 loads/elem MLP, cvt_pk)
//   - pass 1 offset conv barrier-free over resident tiles; each wave owns a
//     full-K 16x16 tile of the 18(pad32)x64 output -> no kt reduction
//   - pass 2 = R8's verified sample+MFMA loop with staging deleted
// prep: R11's coalesced version + fused deform_w copy (2 dispatches total).

typedef __attribute__((ext_vector_type(8))) short short8;
typedef __attribute__((ext_vector_type(4))) float floatx4;

__device__ inline unsigned short f2bf(float f) {  // RNE fp32 -> bf16 bits
  unsigned int u = __float_as_uint(f);
  u += 0x7fff + ((u >> 16) & 1);
  return (unsigned short)(u >> 16);
}
__device__ inline float bflo(unsigned int u) { return __uint_as_float(u << 16); }
__device__ inline float bfhi(unsigned int u) {
  return __uint_as_float(u & 0xffff0000u);
}
// packed fp32x2 -> bf16x2 (RNE); compiler emits v_cvt_pk_bf16_f32
__device__ __forceinline__ unsigned int pkbf(float a, float b) {
  __hip_bfloat162 h = __float22bfloat162_rn(make_float2(a, b));
  unsigned int u;
  __builtin_memcpy(&u, &h, 4);
  return u;
}
__device__ __forceinline__ short8 pack4(unsigned int u0, unsigned int u1,
                                        unsigned int u2, unsigned int u3) {
  short8 b;
  b[0] = (short)(u0 & 0xffff);
  b[1] = (short)(u0 >> 16);
  b[2] = (short)(u1 & 0xffff);
  b[3] = (short)(u1 >> 16);
  b[4] = (short)(u2 & 0xffff);
  b[5] = (short)(u2 >> 16);
  b[6] = (short)(u3 & 0xffff);
  b[7] = (short)(u3 >> 16);
  return b;
}

// ---------------------------------------------------------------------------
// prep (coalesced, R11-verified). Thread g<8192: (o=g>>5, c8=g&31) reads 72
// contiguous floats dw[o][c8*8..+7][0..8] as 18x float4, emits 9 short8
// frags: wfrag[ci=cb*9+n][mt=o>>4][kt=(c8>>2)&1][lane=(c8&3)*16+(o&15)][j].
// g in [8192,9216): same for wfragA (o<18 real, else zeros). Then all
// threads grid-stride copy dw -> out tail (replaces memcpy dispatch).
// ---------------------------------------------------------------------------
__global__ __launch_bounds__(256) void prep_kernel(
    const float* __restrict__ dw, const float* __restrict__ ow,
    unsigned short* __restrict__ wfrag, unsigned short* __restrict__ wfragA,
    float* __restrict__ dwcopy) {
  int g = blockIdx.x * 256 + threadIdx.x;
  if (g < 8192) {
    int o = g >> 5, c8 = g & 31;
    int cb = c8 >> 3, kt = (c8 >> 2) & 1, lh = c8 & 3;
    int mt = o >> 4, lane = lh * 16 + (o & 15);
    float f[72];
    const float4* src = (const float4*)(dw + o * 2304 + c8 * 72);
#pragma unroll
    for (int q = 0; q < 18; ++q) {
      float4 t4 = src[q];
      f[4 * q] = t4.x;
      f[4 * q + 1] = t4.y;
      f[4 * q + 2] = t4.z;
      f[4 * q + 3] = t4.w;
    }
#pragma unroll
    for (int n = 0; n < 9; ++n) {
      int ci = cb * 9 + n;
      short8 v;
#pragma unroll
      for (int j = 0; j < 8; ++j) v[j] = (short)f2bf(f[j * 9 + n]);
      *((short8*)wfrag + ((ci * 16 + mt) * 2 + kt) * 64 + lane) = v;
    }
  } else if (g < 9216) {
    int t = g - 8192;
    int o = t >> 5, c8 = t & 31;
    int cb = c8 >> 3, kt = (c8 >> 2) & 1, lh = c8 & 3;
    int mt = o >> 4, lane = lh * 16 + (o & 15);
    float f[72];
    if (o < 18) {
      const float4* src = (const float4*)(ow + o * 2304 + c8 * 72);
#pragma unroll
      for (int q = 0; q < 18; ++q) {
        float4 t4 = src[q];
        f[4 * q] = t4.x;
        f[4 * q + 1] = t4.y;
        f[4 * q + 2] = t4.z;
        f[4 * q + 3] = t4.w;
      }
    } else {
#pragma unroll
      for (int q = 0; q < 72; ++q) f[q] = 0.f;
    }
#pragma unroll
    for (int n = 0; n < 9; ++n) {
      int ci = cb * 9 + n;
      short8 v;
#pragma unroll
      for (int j = 0; j < 8; ++j) v[j] = (short)f2bf(f[j * 9 + n]);
      *((short8*)wfragA + ((ci * 2 + kt) * 2 + mt) * 64 + lane) = v;
    }
  }
  // coalesced deform_w copy to out tail
  const float4* s = (const float4*)dw;
  float4* d = (float4*)dwcopy;
  for (int i = g; i < 147456; i += 10240) d[i] = s[i];
}

// ---------------------------------------------------------------------------
// Deform sampler for one chunk (cb, n), 8x8 px tile (R8-verified layout):
// thread = (oct = wave, px = lane). oct covers 4 pair-planes (8 channels);
// 16 corner u32 reads -> 4 cvt_pk -> one b128 write into colf.
// colf [nt=4][kt=2][lane=64][j=8]: lane = (px&15)|(qk<<4), nt=px>>4,
// kt=oct>>2, qk=oct&3, j=2q+h (channel cl = oct*8 + 2q + h).
// ---------------------------------------------------------------------------
__device__ __forceinline__ void sample_chunk(
    const unsigned int* __restrict__ xpcb, int n,
    unsigned short* __restrict__ colf, int oct, int px,
    const float (*sw4)[64][4], const int (*scoff)[64]) {
  float4 wq = *(const float4*)&sw4[n][px][0];
  const unsigned int* bp = xpcb + oct * 960 + scoff[n][px];
  unsigned int ua[4], ub[4], uc[4], ud[4];
#pragma unroll
  for (int q = 0; q < 4; ++q) {
    const unsigned int* pl = bp + q * 240;
    ua[q] = pl[0];
    ub[q] = pl[1];
    uc[q] = pl[16];
    ud[q] = pl[17];
  }
  unsigned int w[4];
#pragma unroll
  for (int q = 0; q < 4; ++q) {
    float lo = wq.x * bflo(ua[q]) + wq.y * bflo(ub[q]) + wq.z * bflo(uc[q]) +
               wq.w * bflo(ud[q]);
    float hi = wq.x * bfhi(ua[q]) + wq.y * bfhi(ub[q]) + wq.z * bfhi(uc[q]) +
               wq.w * bfhi(ud[q]);
    w[q] = pkbf(lo, hi);
  }
  uint4 vv = make_uint4(w[0], w[1], w[2], w[3]);
  int nt = px >> 4, kt = oct >> 2, qk = oct & 3;
  *(uint4*)&colf[((nt * 2 + kt) * 64 + ((px & 15) | (qk << 4))) * 8] = vv;
}

// ---------------------------------------------------------------------------
// Fused: stage-once x (4 resident cb tiles) + offset conv + sample + GEMM.
// 8x8 px tile, 256 o, 512 thr (8 waves), 256 blocks = 1/CU.
// LDS: s_xp 4x30720B + colf 16KB + w4 9KB + coff 2.25KB = 147.25KB.
// ---------------------------------------------------------------------------
__global__ __launch_bounds__(512, 2) void deform_kernel(
    const float* __restrict__ x, const float* __restrict__ obias,
    const unsigned short* __restrict__ wfragA,
    const unsigned short* __restrict__ wfrag, const float* __restrict__ bias,
    float* __restrict__ out) {
  int tid = threadIdx.x;
  int b = blockIdx.y, tile = blockIdx.x;
  int h0 = (tile >> 3) * 8, w0 = (tile & 7) * 8;
  int lane = tid & 63, wv = tid >> 6;

  __shared__ unsigned int s_xp[4][7680];  // [cb][pair*240 + ry*16 + rx]
  __shared__ __align__(16) unsigned short s_colf[2][4096];
  __shared__ __align__(16) float s_w4[9][64][4];
  __shared__ int s_coff[9][64];

  const float* xb = x + (size_t)b * 256 * 4096;

  // ---- stage ALL 4 cb tiles once (desc computed once per element; 8
  // independent loads per element for memory-level parallelism) ----
  for (int e = tid; e < 7680; e += 512) {
    int pl = e / 240, pos = e - pl * 240;
    int ry = pos >> 4, rx = pos & 15;
    int gy = h0 - 3 + ry, gx = w0 - 3 + rx;
    bool ok = (rx < 15 && gy >= 0 && gy < 64 && gx >= 0 && gx < 64);
    const float* p0 = xb + (size_t)(pl * 2) * 4096 + (gy * 64 + gx);
#pragma unroll
    for (int cb = 0; cb < 4; ++cb) {
      const float* pc = p0 + cb * 262144;
      float v0 = ok ? pc[0] : 0.f;
      float v1 = ok ? pc[4096] : 0.f;
      s_xp[cb][e] = pkbf(v0, v1);
    }
  }
  __syncthreads();

  // ---- pass 1: offset conv, 18(pad32)x64 output; wave = (mtA=wv>>2,
  // ntA=wv&3) owns one 16x16 tile with FULL K (no cross-wave reduction);
  // barrier-free over resident tiles ----
  {
    int mtA = wv >> 2, ntA = wv & 3;
    int colA = lane & 15, kqA = lane >> 4;
    int pA = ntA * 16 + colA;
    int pyA = pA >> 3, pxA = pA & 7;
    const short8* wAg = (const short8*)wfragA;
    floatx4 aoff = (floatx4)(0.f);
    for (int cb = 0; cb < 4; ++cb) {
      const unsigned int* xp = s_xp[cb];
#pragma unroll
      for (int t = 0; t < 9; ++t) {
        int ty = t / 3, tx = t - ty * 3;
        int ci = cb * 9 + t;
        int po = (pyA + ty + 2) * 16 + (pxA + tx + 2);
#pragma unroll
        for (int kt = 0; kt < 2; ++kt) {
          short8 aA = wAg[((ci * 2 + kt) * 2 + mtA) * 64 + lane];
          const unsigned int* bp = xp + (kt * 16 + kqA * 4) * 240 + po;
          short8 bfr = pack4(bp[0], bp[240], bp[480], bp[720]);
          aoff =
              __builtin_amdgcn_mfma_f32_16x16x32_bf16(aA, bfr, aoff, 0, 0, 0);
        }
      }
    }
    // epilogue: C/D col=lane&15, row=quad*4+r (R6-verified); s_off aliased
    // into colf[1] (dead until chunk-1 sampling, after phase B)
    float* s_off = (float*)&s_colf[1][0];  // [o=18][px=64]
#pragma unroll
    for (int r = 0; r < 4; ++r) {
      int o = mtA * 16 + kqA * 4 + r;
      if (o < 18) s_off[o * 64 + pA] = aoff[r];
    }
  }
  __syncthreads();

  // ---- phase B (R6-verified math): bias + clip fused ----
  {
    const float* s_off = (const float*)&s_colf[1][0];
    for (int e = tid; e < 576; e += 512) {
      int n = e >> 6, pe = e & 63;
      int hy = h0 + (pe >> 3), wx = w0 + (pe & 7);
      float dy = s_off[(2 * n) * 64 + pe] + obias[2 * n];
      float dx = s_off[(2 * n + 1) * 64 + pe] + obias[2 * n + 1];
      dy = fminf(fmaxf(dy, -1.f), 1.f);
      dx = fminf(fmaxf(dx, -1.f), 1.f);
      float fy = dy + (float)(hy - 2 + (n / 3) * 2);
      float fx = dx + (float)(wx - 2 + (n % 3) * 2);
      float y0f = floorf(fy), x0f = floorf(fx);
      float wy1 = fy - y0f, wx1 = fx - x0f;
      float wy0 = 1.f - wy1, wx0 = 1.f - wx1;
      s_coff[n][pe] = ((int)y0f - (h0 - 3)) * 16 + ((int)x0f - (w0 - 3));
      s_w4[n][pe][0] = wy0 * wx0;
      s_w4[n][pe][1] = wy0 * wx1;
      s_w4[n][pe][2] = wy1 * wx0;
      s_w4[n][pe][3] = wy1 * wx1;
    }
  }
  __syncthreads();

  // ---- pass 2: sample + GEMM (R8-verified loop, staging deleted) ----
  int oq = wv >> 1, nh = wv & 1;

  // prologue: sample chunk 0 (cb0, n0) -> colf[0]
  sample_chunk(s_xp[0], 0, s_colf[0], wv, lane, s_w4, s_coff);
  __syncthreads();

  floatx4 acc[4][2];
#pragma unroll
  for (int i = 0; i < 4; ++i)
#pragma unroll
    for (int j = 0; j < 2; ++j) acc[i][j] = (floatx4)(0.f);

  for (int cb = 0; cb < 4; ++cb) {
    for (int n = 0; n < 9; ++n) {
      int ci = cb * 9 + n;
      // A-frags for chunk ci (global/L2; consumed at MFMA below)
      short8 areg[2][4];
      const short8* wg = (const short8*)wfrag + (size_t)ci * 2048;
#pragma unroll
      for (int kt = 0; kt < 2; ++kt)
#pragma unroll
        for (int mi = 0; mi < 4; ++mi)
          areg[kt][mi] = wg[((oq * 4 + mi) * 2 + kt) * 64 + lane];

      // sample chunk ci+1 -> colf[(ci+1)&1] (x tiles all resident)
      if (ci + 1 < 36) {
        int nn = n + 1, cbn = cb;
        if (nn == 9) {
          nn = 0;
          cbn = cb + 1;
        }
        sample_chunk(s_xp[cbn], nn, s_colf[(ci + 1) & 1], wv, lane, s_w4,
                     s_coff);
      }

      // MFMA chunk ci from colf[ci&1]
      const unsigned short* cf = s_colf[ci & 1];
#pragma unroll
      for (int kt = 0; kt < 2; ++kt) {
        short8 bfr[2];
#pragma unroll
        for (int tn = 0; tn < 2; ++tn)
          bfr[tn] =
              *(const short8*)&cf[(((nh * 2 + tn) * 2 + kt) * 64 + lane) * 8];
#pragma unroll
        for (int mi = 0; mi < 4; ++mi)
#pragma unroll
          for (int tn = 0; tn < 2; ++tn)
            acc[mi][tn] = __builtin_amdgcn_mfma_f32_16x16x32_bf16(
                areg[kt][mi], bfr[tn], acc[mi][tn], 0, 0, 0);
      }
      __syncthreads();
    }
  }

  // epilogue (R5-verified C/D layout): col=lane&15, row=quad*4+r
  int quad = lane >> 4, col = lane & 15;
#pragma unroll
  for (int mi = 0; mi < 4; ++mi)
#pragma unroll
    for (int tn = 0; tn < 2; ++tn) {
      int pxo = (nh * 2 + tn) * 16 + col;
      int h = h0 + (pxo >> 3), w = w0 + (pxo & 7);
#pragma unroll
      for (int r = 0; r < 4; ++r) {
        int o = oq * 64 + mi * 16 + quad * 4 + r;
        out[(((size_t)b * 256 + o) * 64 + h) * 64 + w] =
            acc[mi][tn][r] + bias[o];
      }
    }
}

extern "C" void kernel_launch(void* const* d_in, const int* in_sizes, int n_in,
                              void* d_out, int out_size, void* d_ws,
                              size_t ws_size, hipStream_t stream) {
  (void)in_sizes; (void)n_in; (void)out_size; (void)ws_size;
  const float* x        = (const float*)d_in[0];  // (4,256,64,64)
  const float* offset_w = (const float*)d_in[1];  // (18,256,3,3)
  const float* offset_b = (const float*)d_in[2];  // (18,)
  const float* deform_w = (const float*)d_in[3];  // (256,256,3,3)
  const float* deform_b = (const float*)d_in[4];  // (256,)
  float* out = (float*)d_out;

  unsigned short* wfrag = (unsigned short*)d_ws;  // 589824 bf16
  unsigned short* wfragA = wfrag + 589824;        // 73728 bf16

  prep_kernel<<<40, 256, 0, stream>>>(deform_w, offset_w, wfrag, wfragA,
                                      out + 4194304);
  deform_kernel<<<dim3(64, 4), 512, 0, stream>>>(x, offset_b, wfragA, wfrag,
                                                 deform_b, out);
}

// Round 5
// 152.024 us; speedup vs baseline: 1.5351x; 1.0277x over previous
//
#include <hip/hip_runtime.h>
#include <hip/hip_bf16.h>

// B=4, C=256, H=W=64, O=256, K=3, PAD=2, DIL=2; offset conv: 18ch 3x3 p1 d1.
// R13: pass-2 L2-traffic + conflict attack on R12's stage-once structure.
// R12 post-mortem: FETCH fixed (46MB) but deform 87.5us: pass2 ~60us is
// A-frag L2-BW bound (wave pairs duplicated 64KB/CU/chunk ~= 1150cy) +
// 620cy/chunk LDS conflicts (pass1 plane stride 960 u32 == 0 mod 32 banks).
// Fixes: (1) M-split: each wave owns 32 distinct o's, full N=64 -> A-frag
// traffic halves; (2) A-frag prefetch 1 chunk ahead (transient anx[2][2],
// statically indexed); (3) s_xp plane stride 240->241 u32 (quad bank shift)
// + staggered staging (conv(cb) || stage(cb+1), only cb0 exposed).
// All MFMA/sampling/phase-B math layouts identical to R12 (verified chain).

typedef __attribute__((ext_vector_type(8))) short short8;
typedef __attribute__((ext_vector_type(4))) float floatx4;

__device__ inline unsigned short f2bf(float f) {  // RNE fp32 -> bf16 bits
  unsigned int u = __float_as_uint(f);
  u += 0x7fff + ((u >> 16) & 1);
  return (unsigned short)(u >> 16);
}
__device__ inline float bflo(unsigned int u) { return __uint_as_float(u << 16); }
__device__ inline float bfhi(unsigned int u) {
  return __uint_as_float(u & 0xffff0000u);
}
// packed fp32x2 -> bf16x2 (RNE); compiler emits v_cvt_pk_bf16_f32
__device__ __forceinline__ unsigned int pkbf(float a, float b) {
  __hip_bfloat162 h = __float22bfloat162_rn(make_float2(a, b));
  unsigned int u;
  __builtin_memcpy(&u, &h, 4);
  return u;
}
__device__ __forceinline__ short8 pack4(unsigned int u0, unsigned int u1,
                                        unsigned int u2, unsigned int u3) {
  short8 b;
  b[0] = (short)(u0 & 0xffff);
  b[1] = (short)(u0 >> 16);
  b[2] = (short)(u1 & 0xffff);
  b[3] = (short)(u1 >> 16);
  b[4] = (short)(u2 & 0xffff);
  b[5] = (short)(u2 >> 16);
  b[6] = (short)(u3 & 0xffff);
  b[7] = (short)(u3 >> 16);
  return b;
}

// ---------------------------------------------------------------------------
// prep (coalesced, R11-verified). Thread g<8192: (o=g>>5, c8=g&31) reads 72
// contiguous floats dw[o][c8*8..+7][0..8] as 18x float4, emits 9 short8
// frags: wfrag[ci=cb*9+n][mt=o>>4][kt=(c8>>2)&1][lane=(c8&3)*16+(o&15)][j].
// g in [8192,9216): same for wfragA (o<18 real, else zeros). Then all
// threads grid-stride copy dw -> out tail (replaces memcpy dispatch).
// ---------------------------------------------------------------------------
__global__ __launch_bounds__(256) void prep_kernel(
    const float* __restrict__ dw, const float* __restrict__ ow,
    unsigned short* __restrict__ wfrag, unsigned short* __restrict__ wfragA,
    float* __restrict__ dwcopy) {
  int g = blockIdx.x * 256 + threadIdx.x;
  if (g < 8192) {
    int o = g >> 5, c8 = g & 31;
    int cb = c8 >> 3, kt = (c8 >> 2) & 1, lh = c8 & 3;
    int mt = o >> 4, lane = lh * 16 + (o & 15);
    float f[72];
    const float4* src = (const float4*)(dw + o * 2304 + c8 * 72);
#pragma unroll
    for (int q = 0; q < 18; ++q) {
      float4 t4 = src[q];
      f[4 * q] = t4.x;
      f[4 * q + 1] = t4.y;
      f[4 * q + 2] = t4.z;
      f[4 * q + 3] = t4.w;
    }
#pragma unroll
    for (int n = 0; n < 9; ++n) {
      int ci = cb * 9 + n;
      short8 v;
#pragma unroll
      for (int j = 0; j < 8; ++j) v[j] = (short)f2bf(f[j * 9 + n]);
      *((short8*)wfrag + ((ci * 16 + mt) * 2 + kt) * 64 + lane) = v;
    }
  } else if (g < 9216) {
    int t = g - 8192;
    int o = t >> 5, c8 = t & 31;
    int cb = c8 >> 3, kt = (c8 >> 2) & 1, lh = c8 & 3;
    int mt = o >> 4, lane = lh * 16 + (o & 15);
    float f[72];
    if (o < 18) {
      const float4* src = (const float4*)(ow + o * 2304 + c8 * 72);
#pragma unroll
      for (int q = 0; q < 18; ++q) {
        float4 t4 = src[q];
        f[4 * q] = t4.x;
        f[4 * q + 1] = t4.y;
        f[4 * q + 2] = t4.z;
        f[4 * q + 3] = t4.w;
      }
    } else {
#pragma unroll
      for (int q = 0; q < 72; ++q) f[q] = 0.f;
    }
#pragma unroll
    for (int n = 0; n < 9; ++n) {
      int ci = cb * 9 + n;
      short8 v;
#pragma unroll
      for (int j = 0; j < 8; ++j) v[j] = (short)f2bf(f[j * 9 + n]);
      *((short8*)wfragA + ((ci * 2 + kt) * 2 + mt) * 64 + lane) = v;
    }
  }
  // coalesced deform_w copy to out tail
  const float4* s = (const float4*)dw;
  float4* d = (float4*)dwcopy;
  for (int i = g; i < 147456; i += 32768) d[i] = s[i];
}

#define PLSTR 241  // plane stride in u32 (240 data + 1 pad: quad bank shift)

// ---------------------------------------------------------------------------
// Deform sampler for one chunk (cb, n), 8x8 px tile (R8-verified layout):
// thread = (oct = wave, px = lane). oct covers 4 pair-planes (8 channels);
// 16 corner u32 reads -> 4 cvt_pk -> one b128 write into colf.
// colf [nt=4][kt=2][lane=64][j=8]: lane = (px&15)|(qk<<4), nt=px>>4,
// kt=oct>>2, qk=oct&3, j=2q+h (channel cl = oct*8 + 2q + h).
// ---------------------------------------------------------------------------
__device__ __forceinline__ void sample_chunk(
    const unsigned int* __restrict__ xpcb, int n,
    unsigned short* __restrict__ colf, int oct, int px,
    const float (*sw4)[64][4], const int (*scoff)[64]) {
  float4 wq = *(const float4*)&sw4[n][px][0];
  const unsigned int* bp = xpcb + oct * (4 * PLSTR) + scoff[n][px];
  unsigned int ua[4], ub[4], uc[4], ud[4];
#pragma unroll
  for (int q = 0; q < 4; ++q) {
    const unsigned int* pl = bp + q * PLSTR;
    ua[q] = pl[0];
    ub[q] = pl[1];
    uc[q] = pl[16];
    ud[q] = pl[17];
  }
  unsigned int w[4];
#pragma unroll
  for (int q = 0; q < 4; ++q) {
    float lo = wq.x * bflo(ua[q]) + wq.y * bflo(ub[q]) + wq.z * bflo(uc[q]) +
               wq.w * bflo(ud[q]);
    float hi = wq.x * bfhi(ua[q]) + wq.y * bfhi(ub[q]) + wq.z * bfhi(uc[q]) +
               wq.w * bfhi(ud[q]);
    w[q] = pkbf(lo, hi);
  }
  uint4 vv = make_uint4(w[0], w[1], w[2], w[3]);
  int nt = px >> 4, kt = oct >> 2, qk = oct & 3;
  *(uint4*)&colf[((nt * 2 + kt) * 64 + ((px & 15) | (qk << 4))) * 8] = vv;
}

// ---------------------------------------------------------------------------
// Fused: stage-once x (4 resident cb tiles, staggered staging) + offset conv
// + sample + GEMM. 8x8 px tile, 256 o, 512 thr (8 waves), 256 blocks = 1/CU.
// LDS: s_xp 4x7712x4 = 123392 + colf 16384 + w4 9216 + coff 2304 = 151296.
// ---------------------------------------------------------------------------
__global__ __launch_bounds__(512, 2) void deform_kernel(
    const float* __restrict__ x, const float* __restrict__ obias,
    const unsigned short* __restrict__ wfragA,
    const unsigned short* __restrict__ wfrag, const float* __restrict__ bias,
    float* __restrict__ out) {
  int tid = threadIdx.x;
  int b = blockIdx.y, tile = blockIdx.x;
  int h0 = (tile >> 3) * 8, w0 = (tile & 7) * 8;
  int lane = tid & 63, wv = tid >> 6;

  __shared__ unsigned int s_xp[4][32 * PLSTR];  // [cb][plane*241 + ry*16+rx]
  __shared__ __align__(16) unsigned short s_colf[2][4096];
  __shared__ __align__(16) float s_w4[9][64][4];
  __shared__ int s_coff[9][64];

  const float* xb = x + (size_t)b * 256 * 4096;

  // ---- pass 1: staggered stage + offset conv (18(pad32)x64 output) ----
  // wave = (mtA=wv>>2, ntA=wv&3) owns one 16x16 tile with FULL K.
  int mtA = wv >> 2, ntA = wv & 3;
  int colA = lane & 15, kqA = lane >> 4;
  int pA = ntA * 16 + colA;
  int pyA = pA >> 3, pxA = pA & 7;
  const short8* wAg = (const short8*)wfragA;
  floatx4 aoff = (floatx4)(0.f);

  // stage cb0
  for (int e = tid; e < 7680; e += 512) {
    int pl = e / 240, pos = e - pl * 240;
    int ry = pos >> 4, rx = pos & 15;
    int gy = h0 - 3 + ry, gx = w0 - 3 + rx;
    bool ok = (rx < 15 && gy >= 0 && gy < 64 && gx >= 0 && gx < 64);
    const float* p0 = xb + (size_t)(pl * 2) * 4096 + (gy * 64 + gx);
    float v0 = ok ? p0[0] : 0.f;
    float v1 = ok ? p0[4096] : 0.f;
    s_xp[0][pl * PLSTR + pos] = pkbf(v0, v1);
  }
  __syncthreads();

  for (int cb = 0; cb < 4; ++cb) {
    const unsigned int* xp = s_xp[cb];
#pragma unroll
    for (int t = 0; t < 9; ++t) {
      int ty = t / 3, tx = t - ty * 3;
      int ci = cb * 9 + t;
      int po = (pyA + ty + 2) * 16 + (pxA + tx + 2);
#pragma unroll
      for (int kt = 0; kt < 2; ++kt) {
        short8 aA = wAg[((ci * 2 + kt) * 2 + mtA) * 64 + lane];
        const unsigned int* bp = xp + (kt * 16 + kqA * 4) * PLSTR + po;
        short8 bfr = pack4(bp[0], bp[PLSTR], bp[2 * PLSTR], bp[3 * PLSTR]);
        aoff = __builtin_amdgcn_mfma_f32_16x16x32_bf16(aA, bfr, aoff, 0, 0, 0);
      }
    }
    // stage cb+1 (overlaps other waves' conv; own loads pipeline with conv)
    if (cb < 3) {
      for (int e = tid; e < 7680; e += 512) {
        int pl = e / 240, pos = e - pl * 240;
        int ry = pos >> 4, rx = pos & 15;
        int gy = h0 - 3 + ry, gx = w0 - 3 + rx;
        bool ok = (rx < 15 && gy >= 0 && gy < 64 && gx >= 0 && gx < 64);
        const float* p0 =
            xb + (size_t)((cb + 1) * 64 + pl * 2) * 4096 + (gy * 64 + gx);
        float v0 = ok ? p0[0] : 0.f;
        float v1 = ok ? p0[4096] : 0.f;
        s_xp[cb + 1][pl * PLSTR + pos] = pkbf(v0, v1);
      }
    }
    __syncthreads();
  }

  // conv epilogue: C/D col=lane&15, row=quad*4+r (R6-verified); s_off
  // aliased into colf[1] (dead until chunk-1 sampling, after phase B)
  {
    float* s_off = (float*)&s_colf[1][0];  // [o=18][px=64]
#pragma unroll
    for (int r = 0; r < 4; ++r) {
      int o = mtA * 16 + kqA * 4 + r;
      if (o < 18) s_off[o * 64 + pA] = aoff[r];
    }
  }
  __syncthreads();

  // ---- phase B (R6-verified math): bias + clip fused ----
  {
    const float* s_off = (const float*)&s_colf[1][0];
    for (int e = tid; e < 576; e += 512) {
      int n = e >> 6, pe = e & 63;
      int hy = h0 + (pe >> 3), wx = w0 + (pe & 7);
      float dy = s_off[(2 * n) * 64 + pe] + obias[2 * n];
      float dx = s_off[(2 * n + 1) * 64 + pe] + obias[2 * n + 1];
      dy = fminf(fmaxf(dy, -1.f), 1.f);
      dx = fminf(fmaxf(dx, -1.f), 1.f);
      float fy = dy + (float)(hy - 2 + (n / 3) * 2);
      float fx = dx + (float)(wx - 2 + (n % 3) * 2);
      float y0f = floorf(fy), x0f = floorf(fx);
      float wy1 = fy - y0f, wx1 = fx - x0f;
      float wy0 = 1.f - wy1, wx0 = 1.f - wx1;
      s_coff[n][pe] = ((int)y0f - (h0 - 3)) * 16 + ((int)x0f - (w0 - 3));
      s_w4[n][pe][0] = wy0 * wx0;
      s_w4[n][pe][1] = wy0 * wx1;
      s_w4[n][pe][2] = wy1 * wx0;
      s_w4[n][pe][3] = wy1 * wx1;
    }
  }
  __syncthreads();

  // ---- pass 2: sample + GEMM. M-split: wave wv owns o in
  // [wv*32, wv*32+32) (mi 0..1), full N=64 (tn 0..3). A-frag prefetch 1
  // chunk ahead. colf layout/sampling identical to R12. ----

  // prologue: sample chunk 0 -> colf[0]; prefetch areg for ci=0
  sample_chunk(s_xp[0], 0, s_colf[0], wv, lane, s_w4, s_coff);
  short8 areg[2][2];
  {
    const short8* wg = (const short8*)wfrag;
#pragma unroll
    for (int kt = 0; kt < 2; ++kt)
#pragma unroll
      for (int mi = 0; mi < 2; ++mi)
        areg[kt][mi] = wg[((wv * 2 + mi) * 2 + kt) * 64 + lane];
  }
  __syncthreads();

  floatx4 acc[2][4];
#pragma unroll
  for (int i = 0; i < 2; ++i)
#pragma unroll
    for (int j = 0; j < 4; ++j) acc[i][j] = (floatx4)(0.f);

  for (int cb = 0; cb < 4; ++cb) {
    for (int n = 0; n < 9; ++n) {
      int ci = cb * 9 + n;

      // prefetch A-frags for chunk ci+1 (consumed next iter; hides L2)
      short8 anx[2][2];
      if (ci + 1 < 36) {
        const short8* wg = (const short8*)wfrag + (size_t)(ci + 1) * 2048;
#pragma unroll
        for (int kt = 0; kt < 2; ++kt)
#pragma unroll
          for (int mi = 0; mi < 2; ++mi)
            anx[kt][mi] = wg[((wv * 2 + mi) * 2 + kt) * 64 + lane];
      }

      // sample chunk ci+1 -> colf[(ci+1)&1] (x tiles all resident)
      if (ci + 1 < 36) {
        int nn = n + 1, cbn = cb;
        if (nn == 9) {
          nn = 0;
          cbn = cb + 1;
        }
        sample_chunk(s_xp[cbn], nn, s_colf[(ci + 1) & 1], wv, lane, s_w4,
                     s_coff);
      }

      // MFMA chunk ci from colf[ci&1]
      const unsigned short* cf = s_colf[ci & 1];
#pragma unroll
      for (int kt = 0; kt < 2; ++kt) {
        short8 bfr[4];
#pragma unroll
        for (int tn = 0; tn < 4; ++tn)
          bfr[tn] = *(const short8*)&cf[((tn * 2 + kt) * 64 + lane) * 8];
#pragma unroll
        for (int mi = 0; mi < 2; ++mi)
#pragma unroll
          for (int tn = 0; tn < 4; ++tn)
            acc[mi][tn] = __builtin_amdgcn_mfma_f32_16x16x32_bf16(
                areg[kt][mi], bfr[tn], acc[mi][tn], 0, 0, 0);
      }
      __syncthreads();

#pragma unroll
      for (int kt = 0; kt < 2; ++kt)
#pragma unroll
        for (int mi = 0; mi < 2; ++mi) areg[kt][mi] = anx[kt][mi];
    }
  }

  // epilogue (R5-verified C/D layout): col=lane&15, row=quad*4+r
  int quad = lane >> 4, col = lane & 15;
#pragma unroll
  for (int mi = 0; mi < 2; ++mi)
#pragma unroll
    for (int tn = 0; tn < 4; ++tn) {
      int pxo = tn * 16 + col;
      int h = h0 + (pxo >> 3), w = w0 + (pxo & 7);
#pragma unroll
      for (int r = 0; r < 4; ++r) {
        int o = wv * 32 + mi * 16 + quad * 4 + r;
        out[(((size_t)b * 256 + o) * 64 + h) * 64 + w] =
            acc[mi][tn][r] + bias[o];
      }
    }
}

extern "C" void kernel_launch(void* const* d_in, const int* in_sizes, int n_in,
                              void* d_out, int out_size, void* d_ws,
                              size_t ws_size, hipStream_t stream) {
  (void)in_sizes; (void)n_in; (void)out_size; (void)ws_size;
  const float* x        = (const float*)d_in[0];  // (4,256,64,64)
  const float* offset_w = (const float*)d_in[1];  // (18,256,3,3)
  const float* offset_b = (const float*)d_in[2];  // (18,)
  const float* deform_w = (const float*)d_in[3];  // (256,256,3,3)
  const float* deform_b = (const float*)d_in[4];  // (256,)
  float* out = (float*)d_out;

  unsigned short* wfrag = (unsigned short*)d_ws;  // 589824 bf16
  unsigned short* wfragA = wfrag + 589824;        // 73728 bf16

  prep_kernel<<<128, 256, 0, stream>>>(deform_w, offset_w, wfrag, wfragA,
                                       out + 4194304);
  deform_kernel<<<dim3(64, 4), 512, 0, stream>>>(x, offset_b, wfragA, wfrag,
                                                 deform_b, out);
}

// Round 6
// 122.994 us; speedup vs baseline: 1.8975x; 1.2360x over previous
//
#include <hip/hip_runtime.h>
#include <hip/hip_bf16.h>

// B=4, C=256, H=W=64, O=256, K=3, PAD=2, DIL=2; offset conv: 18ch 3x3 p1 d1.
// R14: LDS-pipe attack. R13 post-mortem: PLSTR pad was a null (conflicts
// 5.72M unchanged) -> conflicts are IN the sampler gathers: 64 lanes at
// y*16+x collapse to ~8 banks (y&1)*16+x -> systematic 8-way conflict on all
// 16 b32 gathers/thread/chunk; deform is LDS-pipe-bound (~2200cy/chunk).
// Fix: TRANSPOSED x-tile layout [grp=8][pos=240][q=4] u32 (16B/pos):
//   - sampler corner = 4 consecutive u32 = ONE ds_read_b128 (16->4 reads),
//     bank-balanced (each lane spans 4 banks; footprint = minimal 8 cy)
//   - pass-1 conv gather: 4 b32 -> 1 b128
//   - staging: thread owns (grp,pos): 8 coalesced global loads -> 4 cvt_pk
//     -> 1 b128 LDS write (4x fewer LDS write instrs)
// Channel order per fragment unchanged (grp*4+q == old plane) -> all
// verified MFMA/colf/phase-B layouts byte-identical. Pass-2 M-split +
// A-prefetch kept from R13. prep unchanged.

typedef __attribute__((ext_vector_type(8))) short short8;
typedef __attribute__((ext_vector_type(4))) float floatx4;

__device__ inline unsigned short f2bf(float f) {  // RNE fp32 -> bf16 bits
  unsigned int u = __float_as_uint(f);
  u += 0x7fff + ((u >> 16) & 1);
  return (unsigned short)(u >> 16);
}
__device__ inline float bflo(unsigned int u) { return __uint_as_float(u << 16); }
__device__ inline float bfhi(unsigned int u) {
  return __uint_as_float(u & 0xffff0000u);
}
// packed fp32x2 -> bf16x2 (RNE); compiler emits v_cvt_pk_bf16_f32
__device__ __forceinline__ unsigned int pkbf(float a, float b) {
  __hip_bfloat162 h = __float22bfloat162_rn(make_float2(a, b));
  unsigned int u;
  __builtin_memcpy(&u, &h, 4);
  return u;
}
__device__ __forceinline__ short8 pack4(unsigned int u0, unsigned int u1,
                                        unsigned int u2, unsigned int u3) {
  short8 b;
  b[0] = (short)(u0 & 0xffff);
  b[1] = (short)(u0 >> 16);
  b[2] = (short)(u1 & 0xffff);
  b[3] = (short)(u1 >> 16);
  b[4] = (short)(u2 & 0xffff);
  b[5] = (short)(u2 >> 16);
  b[6] = (short)(u3 & 0xffff);
  b[7] = (short)(u3 >> 16);
  return b;
}

// ---------------------------------------------------------------------------
// prep (coalesced, R11-verified). Thread g<8192: (o=g>>5, c8=g&31) reads 72
// contiguous floats dw[o][c8*8..+7][0..8] as 18x float4, emits 9 short8
// frags: wfrag[ci=cb*9+n][mt=o>>4][kt=(c8>>2)&1][lane=(c8&3)*16+(o&15)][j].
// g in [8192,9216): same for wfragA (o<18 real, else zeros). Then all
// threads grid-stride copy dw -> out tail (replaces memcpy dispatch).
// ---------------------------------------------------------------------------
__global__ __launch_bounds__(256) void prep_kernel(
    const float* __restrict__ dw, const float* __restrict__ ow,
    unsigned short* __restrict__ wfrag, unsigned short* __restrict__ wfragA,
    float* __restrict__ dwcopy) {
  int g = blockIdx.x * 256 + threadIdx.x;
  if (g < 8192) {
    int o = g >> 5, c8 = g & 31;
    int cb = c8 >> 3, kt = (c8 >> 2) & 1, lh = c8 & 3;
    int mt = o >> 4, lane = lh * 16 + (o & 15);
    float f[72];
    const float4* src = (const float4*)(dw + o * 2304 + c8 * 72);
#pragma unroll
    for (int q = 0; q < 18; ++q) {
      float4 t4 = src[q];
      f[4 * q] = t4.x;
      f[4 * q + 1] = t4.y;
      f[4 * q + 2] = t4.z;
      f[4 * q + 3] = t4.w;
    }
#pragma unroll
    for (int n = 0; n < 9; ++n) {
      int ci = cb * 9 + n;
      short8 v;
#pragma unroll
      for (int j = 0; j < 8; ++j) v[j] = (short)f2bf(f[j * 9 + n]);
      *((short8*)wfrag + ((ci * 16 + mt) * 2 + kt) * 64 + lane) = v;
    }
  } else if (g < 9216) {
    int t = g - 8192;
    int o = t >> 5, c8 = t & 31;
    int cb = c8 >> 3, kt = (c8 >> 2) & 1, lh = c8 & 3;
    int mt = o >> 4, lane = lh * 16 + (o & 15);
    float f[72];
    if (o < 18) {
      const float4* src = (const float4*)(ow + o * 2304 + c8 * 72);
#pragma unroll
      for (int q = 0; q < 18; ++q) {
        float4 t4 = src[q];
        f[4 * q] = t4.x;
        f[4 * q + 1] = t4.y;
        f[4 * q + 2] = t4.z;
        f[4 * q + 3] = t4.w;
      }
    } else {
#pragma unroll
      for (int q = 0; q < 72; ++q) f[q] = 0.f;
    }
#pragma unroll
    for (int n = 0; n < 9; ++n) {
      int ci = cb * 9 + n;
      short8 v;
#pragma unroll
      for (int j = 0; j < 8; ++j) v[j] = (short)f2bf(f[j * 9 + n]);
      *((short8*)wfragA + ((ci * 2 + kt) * 2 + mt) * 64 + lane) = v;
    }
  }
  // coalesced deform_w copy to out tail
  const float4* s = (const float4*)dw;
  float4* d = (float4*)dwcopy;
  for (int i = g; i < 147456; i += 32768) d[i] = s[i];
}

// ---------------------------------------------------------------------------
// stage one cb tile into transposed layout: dst[(grp*240+pos)*4 + q] holds
// channel-pair plane grp*4+q at pixel pos (15x15 halo in 15(y)x16(x,15
// valid) grid). Thread per (grp,pos): 8 global loads (stride 4096, gx-
// coalesced across threads) -> 4 cvt_pk -> 1 ds_write_b128.
// ---------------------------------------------------------------------------
__device__ __forceinline__ void stage_tile(unsigned int* __restrict__ dst,
                                           const float* __restrict__ xcb,
                                           int h0, int w0, int tid) {
  for (int e = tid; e < 1920; e += 512) {
    int grp = e / 240, pos = e - grp * 240;
    int ry = pos >> 4, rx = pos & 15;
    int gy = h0 - 3 + ry, gx = w0 - 3 + rx;
    bool ok = (rx < 15 && gy >= 0 && gy < 64 && gx >= 0 && gx < 64);
    unsigned int q0 = 0, q1 = 0, q2 = 0, q3 = 0;
    if (ok) {
      const float* p0 = xcb + (size_t)(grp * 8) * 4096 + (gy * 64 + gx);
      q0 = pkbf(p0[0], p0[4096]);
      q1 = pkbf(p0[8192], p0[12288]);
      q2 = pkbf(p0[16384], p0[20480]);
      q3 = pkbf(p0[24576], p0[28672]);
    }
    *(uint4*)&dst[e * 4] = make_uint4(q0, q1, q2, q3);
  }
}

// ---------------------------------------------------------------------------
// Deform sampler for one chunk (cb, n), 8x8 px tile (R8-verified colf
// layout): thread = (oct = wave, px = lane). oct covers planes oct*4+q
// (8 channels). 4 corner ds_read_b128 (bank-balanced) -> bilinear -> 4
// cvt_pk -> one b128 write into colf.
// colf [nt=4][kt=2][lane=64][j=8]: lane = (px&15)|(qk<<4), nt=px>>4,
// kt=oct>>2, qk=oct&3, j=2q+h (channel cl = oct*8 + 2q + h).
// ---------------------------------------------------------------------------
__device__ __forceinline__ void sample_chunk(
    const unsigned int* __restrict__ xpcb, int n,
    unsigned short* __restrict__ colf, int oct, int px,
    const float (*sw4)[64][4], const int (*scoff)[64]) {
  float4 wq = *(const float4*)&sw4[n][px][0];
  const unsigned int* bp = xpcb + oct * 960 + scoff[n][px];
  uint4 A = *(const uint4*)(bp);       // corner (y0,x0),   q=0..3
  uint4 Bv = *(const uint4*)(bp + 4);  // corner (y0,x0+1)
  uint4 Cv = *(const uint4*)(bp + 64); // corner (y0+1,x0)
  uint4 Dv = *(const uint4*)(bp + 68); // corner (y0+1,x0+1)
  unsigned int w[4];
#define BILIN(qi, ua, ub, uc, ud)                                       \
  {                                                                     \
    float lo = wq.x * bflo(ua) + wq.y * bflo(ub) + wq.z * bflo(uc) +    \
               wq.w * bflo(ud);                                         \
    float hi = wq.x * bfhi(ua) + wq.y * bfhi(ub) + wq.z * bfhi(uc) +    \
               wq.w * bfhi(ud);                                         \
    w[qi] = pkbf(lo, hi);                                               \
  }
  BILIN(0, A.x, Bv.x, Cv.x, Dv.x)
  BILIN(1, A.y, Bv.y, Cv.y, Dv.y)
  BILIN(2, A.z, Bv.z, Cv.z, Dv.z)
  BILIN(3, A.w, Bv.w, Cv.w, Dv.w)
#undef BILIN
  uint4 vv = make_uint4(w[0], w[1], w[2], w[3]);
  int nt = px >> 4, kt = oct >> 2, qk = oct & 3;
  *(uint4*)&colf[((nt * 2 + kt) * 64 + ((px & 15) | (qk << 4))) * 8] = vv;
}

// ---------------------------------------------------------------------------
// Fused: stage-once x (4 resident cb tiles, staggered) + offset conv +
// sample + GEMM. 8x8 px tile, 256 o, 512 thr (8 waves), 256 blocks = 1/CU.
// LDS: s_xp 4x7680x4 = 122880 + colf 16384 + w4 9216 + coff 2304 = 150784.
// ---------------------------------------------------------------------------
__global__ __launch_bounds__(512, 2) void deform_kernel(
    const float* __restrict__ x, const float* __restrict__ obias,
    const unsigned short* __restrict__ wfragA,
    const unsigned short* __restrict__ wfrag, const float* __restrict__ bias,
    float* __restrict__ out) {
  int tid = threadIdx.x;
  int b = blockIdx.y, tile = blockIdx.x;
  int h0 = (tile >> 3) * 8, w0 = (tile & 7) * 8;
  int lane = tid & 63, wv = tid >> 6;

  __shared__ __align__(16) unsigned int s_xp[4][7680];  // [cb][(grp*240+pos)*4+q]
  __shared__ __align__(16) unsigned short s_colf[2][4096];
  __shared__ __align__(16) float s_w4[9][64][4];
  __shared__ int s_coff[9][64];

  const float* xb = x + (size_t)b * 256 * 4096;

  // ---- pass 1: staggered stage + offset conv (18(pad32)x64 output) ----
  // wave = (mtA=wv>>2, ntA=wv&3) owns one 16x16 tile with FULL K.
  int mtA = wv >> 2, ntA = wv & 3;
  int colA = lane & 15, kqA = lane >> 4;
  int pA = ntA * 16 + colA;
  int pyA = pA >> 3, pxA = pA & 7;
  const short8* wAg = (const short8*)wfragA;
  floatx4 aoff = (floatx4)(0.f);

  stage_tile(s_xp[0], xb, h0, w0, tid);
  __syncthreads();

  for (int cb = 0; cb < 4; ++cb) {
    const unsigned int* xp = s_xp[cb];
#pragma unroll
    for (int t = 0; t < 9; ++t) {
      int ty = t / 3, tx = t - ty * 3;
      int ci = cb * 9 + t;
      int po = (pyA + ty + 2) * 16 + (pxA + tx + 2);
#pragma unroll
      for (int kt = 0; kt < 2; ++kt) {
        short8 aA = wAg[((ci * 2 + kt) * 2 + mtA) * 64 + lane];
        uint4 X = *(const uint4*)(xp + (kt * 4 + kqA) * 960 + po * 4);
        short8 bfr = pack4(X.x, X.y, X.z, X.w);
        aoff = __builtin_amdgcn_mfma_f32_16x16x32_bf16(aA, bfr, aoff, 0, 0, 0);
      }
    }
    // stage cb+1 (overlaps other waves' conv; own loads pipeline with conv)
    if (cb < 3) stage_tile(s_xp[cb + 1], xb + (cb + 1) * 262144, h0, w0, tid);
    __syncthreads();
  }

  // conv epilogue: C/D col=lane&15, row=quad*4+r (R6-verified); s_off
  // aliased into colf[1] (dead until chunk-1 sampling, after phase B)
  {
    float* s_off = (float*)&s_colf[1][0];  // [o=18][px=64]
#pragma unroll
    for (int r = 0; r < 4; ++r) {
      int o = mtA * 16 + kqA * 4 + r;
      if (o < 18) s_off[o * 64 + pA] = aoff[r];
    }
  }
  __syncthreads();

  // ---- phase B (R6-verified math): bias + clip fused ----
  {
    const float* s_off = (const float*)&s_colf[1][0];
    for (int e = tid; e < 576; e += 512) {
      int n = e >> 6, pe = e & 63;
      int hy = h0 + (pe >> 3), wx = w0 + (pe & 7);
      float dy = s_off[(2 * n) * 64 + pe] + obias[2 * n];
      float dx = s_off[(2 * n + 1) * 64 + pe] + obias[2 * n + 1];
      dy = fminf(fmaxf(dy, -1.f), 1.f);
      dx = fminf(fmaxf(dx, -1.f), 1.f);
      float fy = dy + (float)(hy - 2 + (n / 3) * 2);
      float fx = dx + (float)(wx - 2 + (n % 3) * 2);
      float y0f = floorf(fy), x0f = floorf(fx);
      float wy1 = fy - y0f, wx1 = fx - x0f;
      float wy0 = 1.f - wy1, wx0 = 1.f - wx1;
      // premultiplied by 4: u32 index of q0 at (y0,x0) within a grp
      s_coff[n][pe] =
          (((int)y0f - (h0 - 3)) * 16 + ((int)x0f - (w0 - 3))) * 4;
      s_w4[n][pe][0] = wy0 * wx0;
      s_w4[n][pe][1] = wy0 * wx1;
      s_w4[n][pe][2] = wy1 * wx0;
      s_w4[n][pe][3] = wy1 * wx1;
    }
  }
  __syncthreads();

  // ---- pass 2: sample + GEMM. M-split: wave wv owns o in
  // [wv*32, wv*32+32) (mi 0..1), full N=64 (tn 0..3). A-frag prefetch 1
  // chunk ahead. colf layout/sampling identical chain-verified. ----

  // prologue: sample chunk 0 -> colf[0]; prefetch areg for ci=0
  sample_chunk(s_xp[0], 0, s_colf[0], wv, lane, s_w4, s_coff);
  short8 areg[2][2];
  {
    const short8* wg = (const short8*)wfrag;
#pragma unroll
    for (int kt = 0; kt < 2; ++kt)
#pragma unroll
      for (int mi = 0; mi < 2; ++mi)
        areg[kt][mi] = wg[((wv * 2 + mi) * 2 + kt) * 64 + lane];
  }
  __syncthreads();

  floatx4 acc[2][4];
#pragma unroll
  for (int i = 0; i < 2; ++i)
#pragma unroll
    for (int j = 0; j < 4; ++j) acc[i][j] = (floatx4)(0.f);

  for (int cb = 0; cb < 4; ++cb) {
    for (int n = 0; n < 9; ++n) {
      int ci = cb * 9 + n;

      // prefetch A-frags for chunk ci+1 (consumed next iter; hides L2)
      short8 anx[2][2];
      if (ci + 1 < 36) {
        const short8* wg = (const short8*)wfrag + (size_t)(ci + 1) * 2048;
#pragma unroll
        for (int kt = 0; kt < 2; ++kt)
#pragma unroll
          for (int mi = 0; mi < 2; ++mi)
            anx[kt][mi] = wg[((wv * 2 + mi) * 2 + kt) * 64 + lane];
      }

      // sample chunk ci+1 -> colf[(ci+1)&1] (x tiles all resident)
      if (ci + 1 < 36) {
        int nn = n + 1, cbn = cb;
        if (nn == 9) {
          nn = 0;
          cbn = cb + 1;
        }
        sample_chunk(s_xp[cbn], nn, s_colf[(ci + 1) & 1], wv, lane, s_w4,
                     s_coff);
      }

      // MFMA chunk ci from colf[ci&1]
      const unsigned short* cf = s_colf[ci & 1];
#pragma unroll
      for (int kt = 0; kt < 2; ++kt) {
        short8 bfr[4];
#pragma unroll
        for (int tn = 0; tn < 4; ++tn)
          bfr[tn] = *(const short8*)&cf[((tn * 2 + kt) * 64 + lane) * 8];
#pragma unroll
        for (int mi = 0; mi < 2; ++mi)
#pragma unroll
          for (int tn = 0; tn < 4; ++tn)
            acc[mi][tn] = __builtin_amdgcn_mfma_f32_16x16x32_bf16(
                areg[kt][mi], bfr[tn], acc[mi][tn], 0, 0, 0);
      }
      __syncthreads();

#pragma unroll
      for (int kt = 0; kt < 2; ++kt)
#pragma unroll
        for (int mi = 0; mi < 2; ++mi) areg[kt][mi] = anx[kt][mi];
    }
  }

  // epilogue (R5-verified C/D layout): col=lane&15, row=quad*4+r
  int quad = lane >> 4, col = lane & 15;
#pragma unroll
  for (int mi = 0; mi < 2; ++mi)
#pragma unroll
    for (int tn = 0; tn < 4; ++tn) {
      int pxo = tn * 16 + col;
      int h = h0 + (pxo >> 3), w = w0 + (pxo & 7);
#pragma unroll
      for (int r = 0; r < 4; ++r) {
        int o = wv * 32 + mi * 16 + quad * 4 + r;
        out[(((size_t)b * 256 + o) * 64 + h) * 64 + w] =
            acc[mi][tn][r] + bias[o];
      }
    }
}

extern "C" void kernel_launch(void* const* d_in, const int* in_sizes, int n_in,
                              void* d_out, int out_size, void* d_ws,
                              size_t ws_size, hipStream_t stream) {
  (void)in_sizes; (void)n_in; (void)out_size; (void)ws_size;
  const float* x        = (const float*)d_in[0];  // (4,256,64,64)
  const float* offset_w = (const float*)d_in[1];  // (18,256,3,3)
  const float* offset_b = (const float*)d_in[2];  // (18,)
  const float* deform_w = (const float*)d_in[3];  // (256,256,3,3)
  const float* deform_b = (const float*)d_in[4];  // (256,)
  float* out = (float*)d_out;

  unsigned short* wfrag = (unsigned short*)d_ws;  // 589824 bf16
  unsigned short* wfragA = wfrag + 589824;        // 73728 bf16

  prep_kernel<<<128, 256, 0, stream>>>(deform_w, offset_w, wfrag, wfragA,
                                       out + 4194304);
  deform_kernel<<<dim3(64, 4), 512, 0, stream>>>(x, offset_b, wfragA, wfrag,
                                                 deform_b, out);
}